// Round 15
// baseline (6670.396 us; speedup 1.0000x reference)
//
#include <hip/hip_runtime.h>

#define Tt  512
#define Hd  1024
#define Cc  10
#define HBHALF (256 * 1024)   // elements per h buffer [256][1024]

typedef short bf16x8 __attribute__((ext_vector_type(8)));
typedef float f32x4 __attribute__((ext_vector_type(4)));

__device__ __forceinline__ unsigned short f2bf(float f) {
  unsigned u = __builtin_bit_cast(unsigned, f);
  u = (u + 0x7FFFu + ((u >> 16) & 1u)) >> 16;   // RTNE
  return (unsigned short)u;
}
__device__ __forceinline__ float bf2f(unsigned short s) {
  unsigned u = ((unsigned)s) << 16;
  return __builtin_bit_cast(float, u);
}
__device__ __forceinline__ float sigmf_(float z) { return 1.0f / (1.0f + __expf(-z)); }
__device__ __forceinline__ float tanhf_(float z) { return 1.0f - 2.0f / (__expf(2.0f * z) + 1.0f); }

// ---- prep: fuse+transpose Wh (f32 [k][col]) -> whT (bf16 [gate][col][k]) ----
__global__ __launch_bounds__(256) void lstm_prep(
    const float* __restrict__ wgh, const float* __restrict__ wih,
    const float* __restrict__ wfh, const float* __restrict__ woh,
    unsigned short* __restrict__ whT)
{
  __shared__ float tile[64][65];
  const int bid = blockIdx.x;
  const int q  = bid >> 8;
  const int ct = (bid >> 4) & 15;
  const int kt = bid & 15;
  const float* w = (q == 0) ? wgh : (q == 1) ? wih : (q == 2) ? wfh : woh;
  const int tid = threadIdx.x;
  const int tc = tid & 63, tr = tid >> 6;
  #pragma unroll
  for (int i = 0; i < 16; ++i) {
    int kk = i * 4 + tr;
    tile[kk][tc] = w[(size_t)(kt * 64 + kk) * Hd + ct * 64 + tc];
  }
  __syncthreads();
  #pragma unroll
  for (int i = 0; i < 16; ++i) {
    int cc = i * 4 + tr;
    whT[(size_t)(q * 1024 + ct * 64 + cc) * Hd + kt * 64 + tc] = f2bf(tile[tc][cc]);
  }
}

// ---- transpose x [256][512] -> xT [512][256] (coalesced per-step reads) ----
__global__ __launch_bounds__(256) void x_prep(
    const float* __restrict__ x, float* __restrict__ xT)
{
  __shared__ float tile[32][33];
  const int bx = blockIdx.x & 15;   // t tile
  const int by = blockIdx.x >> 4;   // r tile
  const int tc = threadIdx.x & 31, tr = threadIdx.x >> 5;
  #pragma unroll
  for (int i = 0; i < 4; ++i) {
    int rr = i * 8 + tr;
    tile[rr][tc] = x[(size_t)(by * 32 + rr) * Tt + bx * 32 + tc];
  }
  __syncthreads();
  #pragma unroll
  for (int i = 0; i < 4; ++i) {
    int tt = i * 8 + tr;
    xT[(size_t)(bx * 32 + tt) * 256 + by * 32 + tc] = tile[tc][tt];
  }
}

// ---- t = 0: h_0 = 0, c_0 = 0  =>  z = x*wx + b (no GEMM, no staging) ----
__global__ __launch_bounds__(512) void lstm_step0(
    const float* __restrict__ xT,
    const float* __restrict__ wgx, const float* __restrict__ wix,
    const float* __restrict__ wfx, const float* __restrict__ wox,
    const float* __restrict__ bg,  const float* __restrict__ bi,
    const float* __restrict__ bfp, const float* __restrict__ bo,
    unsigned short* __restrict__ h1,   // parity-1 h buffer
    float* __restrict__ cbuf)
{
  int idx = blockIdx.x * 512 + threadIdx.x;   // 512 blocks -> 256*1024
  int r = idx >> 10, hc = idx & 1023;
  float xv = xT[r];                           // t = 0 column
  float G = tanhf_(xv * wgx[hc] + bg[hc]);
  float I = sigmf_(xv * wix[hc] + bi[hc]);
  float O = sigmf_(xv * wox[hc] + bo[hc]);
  (void)bfp; (void)wfx;                       // f-gate multiplies c_0 = 0
  float c = G * I;
  cbuf[idx] = c;
  h1[idx] = f2bf(tanhf_(c) * O);
}

// ---- one timestep (t >= 1): all global latencies overlapped pre-barrier ----
__global__ __launch_bounds__(512, 2) void lstm_step(
    const unsigned short* __restrict__ whT,
    const float* __restrict__ xT,
    const float* __restrict__ wgx, const float* __restrict__ wix,
    const float* __restrict__ wfx, const float* __restrict__ wox,
    const float* __restrict__ bg,  const float* __restrict__ bi,
    const float* __restrict__ bfp, const float* __restrict__ bo,
    const unsigned short* __restrict__ hR,   // h_t   [256][1024] bf16
    unsigned short* __restrict__ hW,         // h_t+1 [256][1024] bf16
    float* __restrict__ cbuf,                // c     [256][1024] f32
    int t)
{
  extern __shared__ char smem[];
  char*  hls  = smem;                        // [32 rows][2048B] swizzled bf16, 64KB
  float* zbuf = (float*)(smem + 65536);      // [32][128] f32, 16KB
  __shared__ float xsh[32];

  const int tid = threadIdx.x;
  const int l   = tid & 63;
  const int w   = tid >> 6;        // wave 0..7
  const int cb  = blockIdx.x & 31; // col block (cb%8 -> XCD round-robin)
  const int rg  = blockIdx.x >> 5; // row group
  const int r0  = rg * 32;
  const int hc0 = cb * 32;

  if (tid < 32) xsh[tid] = xT[(size_t)t * 256 + r0 + tid];

  // ---- (1) stage h rows [r0, r0+32) -> LDS (async, pre-swizzled source) ----
  {
    int rbase = w * 4;
    #pragma unroll
    for (int i = 0; i < 8; ++i) {
      int r = rbase + (i >> 1);
      int half = i & 1;
      char* ldsb = hls + r * 2048 + half * 1024;    // wave-uniform, linear dest
      int m = half * 64 + l;                         // dest 16B-chunk index
      int srcc = m ^ (r & 7);                        // inverse swizzle on source
      const char* gp = (const char*)hR + (((size_t)(r0 + r) << 10) + srcc * 8) * 2;
      __builtin_amdgcn_global_load_lds(gp, ldsb, 16, 0, 0);
    }
  }

  // ---- (2) B-fragments -> registers, in flight PARALLEL with staging ----
  const int q   = w >> 1;
  const int lc  = l & 15;
  const int bcol = hc0 + ((w & 1) << 4) + lc;
  const unsigned short* wcol = whT + (size_t)(q * 1024 + bcol) * Hd + (l >> 4) * 8;
  bf16x8 bq[32];
  #pragma unroll
  for (int kc = 0; kc < 32; ++kc) bq[kc] = *(const bf16x8*)(wcol + kc * 32);

  // ---- (3) per-lane gate constants + c state, also in flight ----
  const float* wxp = (q == 0) ? wgx : (q == 1) ? wix : (q == 2) ? wfx : wox;
  const float* bbp = (q == 0) ? bg  : (q == 1) ? bi  : (q == 2) ? bfp : bo;
  const float wxv = wxp[bcol];
  const float bbv = bbp[bcol];

  const int r_a = tid >> 5, hc_a = tid & 31;
  const int r_b = (tid + 512) >> 5;
  const size_t ci_a = (size_t)(r0 + r_a) * Hd + hc0 + hc_a;
  const size_t ci_b = (size_t)(r0 + r_b) * Hd + hc0 + hc_a;
  const float c_a = cbuf[ci_a];
  const float c_b = cbuf[ci_b];

  __syncthreads();   // ONE drain: staging + B + c + x latencies all overlapped

  // ---- acc init = bias + x*wx (C/D layout: col=l&15, row=(l>>4)*4+p) ----
  const int rb4 = (l >> 4) * 4;
  f32x4 acc0, acc1;
  #pragma unroll
  for (int p = 0; p < 4; ++p) {
    acc0[p] = bbv + xsh[rb4 + p] * wxv;
    acc1[p] = bbv + xsh[rb4 + p + 16] * wxv;
  }

  // ---- pure LDS+register MFMA loop ----
  const int roff0 = lc * 2048;
  const int roff1 = roff0 + 16 * 2048;
  const int swz   = (l & 7) << 4;
  const int kboff = (l >> 4) * 16;
  #pragma unroll
  for (int kc = 0; kc < 32; ++kc) {
    int boff = (kc * 64 + kboff) ^ swz;
    bf16x8 a0 = *(const bf16x8*)(hls + roff0 + boff);
    bf16x8 a1 = *(const bf16x8*)(hls + roff1 + boff);
    acc0 = __builtin_amdgcn_mfma_f32_16x16x32_bf16(a0, bq[kc], acc0, 0, 0, 0);
    acc1 = __builtin_amdgcn_mfma_f32_16x16x32_bf16(a1, bq[kc], acc1, 0, 0, 0);
  }

  // ---- acc -> zbuf (full z: bias + x-term already included) ----
  {
    int colz = (w << 4) + lc;
    #pragma unroll
    for (int p = 0; p < 4; ++p) {
      zbuf[(rb4 + p) * 128 + colz]      = acc0[p];
      zbuf[(rb4 + p + 16) * 128 + colz] = acc1[p];
    }
  }
  __syncthreads();

  // ---- lean epilogue: gates + c update, write h' and c ----
  float cn_a, cn_b;
  {
    float zg = zbuf[r_a * 128 +       hc_a];
    float zi = zbuf[r_a * 128 +  32 + hc_a];
    float zf = zbuf[r_a * 128 +  64 + hc_a];
    float zo = zbuf[r_a * 128 +  96 + hc_a];
    float G = tanhf_(zg), I = sigmf_(zi), F = sigmf_(zf), O = sigmf_(zo);
    cn_a = G * I + c_a * F;
    hW[ci_a] = f2bf(tanhf_(cn_a) * O);
  }
  {
    float zg = zbuf[r_b * 128 +       hc_a];
    float zi = zbuf[r_b * 128 +  32 + hc_a];
    float zf = zbuf[r_b * 128 +  64 + hc_a];
    float zo = zbuf[r_b * 128 +  96 + hc_a];
    float G = tanhf_(zg), I = sigmf_(zi), F = sigmf_(zf), O = sigmf_(zo);
    cn_b = G * I + c_b * F;
    hW[ci_b] = f2bf(tanhf_(cn_b) * O);
  }
  cbuf[ci_a] = cn_a;
  cbuf[ci_b] = cn_b;
}

// ---- projection + softmax ----
__global__ __launch_bounds__(256) void lstm_final(
    const unsigned short* __restrict__ h, const float* __restrict__ wph,
    const float* __restrict__ bp, float* __restrict__ out)
{
  __shared__ float zrow[16][10];
  const int tid = threadIdx.x;
  if (tid < 160) {
    int rr = tid / 10, c = tid - rr * 10;
    int r = blockIdx.x * 16 + rr;
    float acc = bp[c];
    for (int k8 = 0; k8 < 128; ++k8) {
      bf16x8 hv = *(const bf16x8*)(h + (size_t)r * Hd + k8 * 8);
      #pragma unroll
      for (int e = 0; e < 8; ++e)
        acc += bf2f((unsigned short)hv[e]) * wph[(k8 * 8 + e) * Cc + c];
    }
    zrow[rr][c] = acc;
  }
  __syncthreads();
  if (tid < 16) {
    int r = blockIdx.x * 16 + tid;
    float m = -1e30f;
    #pragma unroll
    for (int cc = 0; cc < Cc; ++cc) m = fmaxf(m, zrow[tid][cc]);
    float s = 0.f;
    float ev[Cc];
    #pragma unroll
    for (int cc = 0; cc < Cc; ++cc) { ev[cc] = __expf(zrow[tid][cc] - m); s += ev[cc]; }
    float inv = 1.0f / s;
    #pragma unroll
    for (int cc = 0; cc < Cc; ++cc) out[r * Cc + cc] = ev[cc] * inv;
  }
}

extern "C" void kernel_launch(void* const* d_in, const int* in_sizes, int n_in,
                              void* d_out, int out_size, void* d_ws, size_t ws_size,
                              hipStream_t stream) {
  const float* x   = (const float*)d_in[0];
  const float* wgx = (const float*)d_in[1];
  const float* wgh = (const float*)d_in[2];
  const float* bg  = (const float*)d_in[3];
  const float* wix = (const float*)d_in[4];
  const float* wih = (const float*)d_in[5];
  const float* bi  = (const float*)d_in[6];
  const float* wfx = (const float*)d_in[7];
  const float* wfh = (const float*)d_in[8];
  const float* bfp = (const float*)d_in[9];
  const float* wox = (const float*)d_in[10];
  const float* woh = (const float*)d_in[11];
  const float* bo  = (const float*)d_in[12];
  const float* wph = (const float*)d_in[13];
  const float* bp  = (const float*)d_in[14];
  float* out = (float*)d_out;

  // d_ws layout: whT 8.0MB | hbuf 2x512KB | cbuf 1MB | xT 512KB
  unsigned short* whT  = (unsigned short*)d_ws;
  unsigned short* hbuf = (unsigned short*)((char*)d_ws + (size_t)4 * 1024 * Hd * 2);
  float* cbuf = (float*)((char*)hbuf + (size_t)2 * HBHALF * 2);
  float* xT   = (float*)((char*)cbuf + (size_t)HBHALF * 4);

  size_t shmem = 65536 + 16384;   // 80KB dynamic (+ static xsh)
  hipFuncSetAttribute((const void*)lstm_step,
                      hipFuncAttributeMaxDynamicSharedMemorySize, (int)shmem);

  lstm_prep<<<1024, 256, 0, stream>>>(wgh, wih, wfh, woh, whT);
  x_prep<<<128, 256, 0, stream>>>(x, xT);

  // t = 0: writes h_1 (parity 1) and c_1 fully -> no memsets needed
  lstm_step0<<<512, 512, 0, stream>>>(xT, wgx, wix, wfx, wox,
                                      bg, bi, bfp, bo,
                                      hbuf + HBHALF, cbuf);

  for (int t = 1; t < Tt; ++t) {
    const unsigned short* hR = hbuf + (size_t)(t & 1) * HBHALF;
    unsigned short*       hW = hbuf + (size_t)((t + 1) & 1) * HBHALF;
    lstm_step<<<256, 512, shmem, stream>>>(whT, xT, wgx, wix, wfx, wox,
                                           bg, bi, bfp, bo, hR, hW, cbuf, t);
  }

  lstm_final<<<16, 256, 0, stream>>>(hbuf /* parity 0 = h_T */, wph, bp, out);
}

// Round 16
// 5533.811 us; speedup vs baseline: 1.2054x; 1.2054x over previous
//
#include <hip/hip_runtime.h>

#define Tt  512
#define Hd  1024
#define Cc  10
#define HBHALF (256 * 1024)   // elements per h buffer [256][1024]

typedef short bf16x8 __attribute__((ext_vector_type(8)));
typedef float f32x4 __attribute__((ext_vector_type(4)));

__device__ __forceinline__ unsigned short f2bf(float f) {
  unsigned u = __builtin_bit_cast(unsigned, f);
  u = (u + 0x7FFFu + ((u >> 16) & 1u)) >> 16;   // RTNE
  return (unsigned short)u;
}
__device__ __forceinline__ float bf2f(unsigned short s) {
  unsigned u = ((unsigned)s) << 16;
  return __builtin_bit_cast(float, u);
}
__device__ __forceinline__ float sigmf_(float z) { return 1.0f / (1.0f + __expf(-z)); }
__device__ __forceinline__ float tanhf_(float z) { return 1.0f - 2.0f / (__expf(2.0f * z) + 1.0f); }

// ---- prep: fuse+transpose Wh (f32 [k][col]) -> whT (bf16 [gate][col][k]) ----
__global__ __launch_bounds__(256) void lstm_prep(
    const float* __restrict__ wgh, const float* __restrict__ wih,
    const float* __restrict__ wfh, const float* __restrict__ woh,
    unsigned short* __restrict__ whT)
{
  __shared__ float tile[64][65];
  const int bid = blockIdx.x;
  const int q  = bid >> 8;
  const int ct = (bid >> 4) & 15;
  const int kt = bid & 15;
  const float* w = (q == 0) ? wgh : (q == 1) ? wih : (q == 2) ? wfh : woh;
  const int tid = threadIdx.x;
  const int tc = tid & 63, tr = tid >> 6;
  #pragma unroll
  for (int i = 0; i < 16; ++i) {
    int kk = i * 4 + tr;
    tile[kk][tc] = w[(size_t)(kt * 64 + kk) * Hd + ct * 64 + tc];
  }
  __syncthreads();
  #pragma unroll
  for (int i = 0; i < 16; ++i) {
    int cc = i * 4 + tr;
    whT[(size_t)(q * 1024 + ct * 64 + cc) * Hd + kt * 64 + tc] = f2bf(tile[tc][cc]);
  }
}

// ---- transpose x [256][512] -> xT [512][256] (coalesced per-step reads) ----
__global__ __launch_bounds__(256) void x_prep(
    const float* __restrict__ x, float* __restrict__ xT)
{
  __shared__ float tile[32][33];
  const int bx = blockIdx.x & 15;   // t tile
  const int by = blockIdx.x >> 4;   // r tile
  const int tc = threadIdx.x & 31, tr = threadIdx.x >> 5;
  #pragma unroll
  for (int i = 0; i < 4; ++i) {
    int rr = i * 8 + tr;
    tile[rr][tc] = x[(size_t)(by * 32 + rr) * Tt + bx * 32 + tc];
  }
  __syncthreads();
  #pragma unroll
  for (int i = 0; i < 4; ++i) {
    int tt = i * 8 + tr;
    xT[(size_t)(bx * 32 + tt) * 256 + by * 32 + tc] = tile[tc][tt];
  }
}

// ---- t = 0: h_0 = 0, c_0 = 0  =>  z = x*wx + b (no GEMM, no staging) ----
__global__ __launch_bounds__(512) void lstm_step0(
    const float* __restrict__ xT,
    const float* __restrict__ wgx, const float* __restrict__ wix,
    const float* __restrict__ wfx, const float* __restrict__ wox,
    const float* __restrict__ bg,  const float* __restrict__ bi,
    const float* __restrict__ bfp, const float* __restrict__ bo,
    unsigned short* __restrict__ h1,   // parity-1 h buffer
    float* __restrict__ cbuf)
{
  int idx = blockIdx.x * 512 + threadIdx.x;   // 512 blocks -> 256*1024
  int r = idx >> 10, hc = idx & 1023;
  float xv = xT[r];                           // t = 0 column
  float G = tanhf_(xv * wgx[hc] + bg[hc]);
  float I = sigmf_(xv * wix[hc] + bi[hc]);
  float O = sigmf_(xv * wox[hc] + bo[hc]);
  (void)bfp; (void)wfx;                       // f-gate multiplies c_0 = 0
  float c = G * I;
  cbuf[idx] = c;
  h1[idx] = f2bf(tanhf_(c) * O);
}

// ---- one timestep (t >= 1): v9 geometry, B streamed in-loop, lean epilogue ----
__global__ __launch_bounds__(512) void lstm_step(
    const unsigned short* __restrict__ whT,
    const float* __restrict__ xT,
    const float* __restrict__ wgx, const float* __restrict__ wix,
    const float* __restrict__ wfx, const float* __restrict__ wox,
    const float* __restrict__ bg,  const float* __restrict__ bi,
    const float* __restrict__ bfp, const float* __restrict__ bo,
    const unsigned short* __restrict__ hR,   // h_t   [256][1024] bf16
    unsigned short* __restrict__ hW,         // h_t+1 [256][1024] bf16
    float* __restrict__ cbuf,                // c     [256][1024] f32
    int t)
{
  extern __shared__ char smem[];
  char*  hls  = smem;                        // [32 rows][2048B] swizzled bf16, 64KB
  float* zbuf = (float*)(smem + 65536);      // [32][128] f32, 16KB
  __shared__ float xsh[32];

  const int tid = threadIdx.x;
  const int l   = tid & 63;
  const int w   = tid >> 6;        // wave 0..7
  const int cb  = blockIdx.x & 31; // col block (cb%8 -> XCD round-robin)
  const int rg  = blockIdx.x >> 5; // row group
  const int r0  = rg * 32;
  const int hc0 = cb * 32;

  if (tid < 32) xsh[tid] = xT[(size_t)t * 256 + r0 + tid];

  // ---- stage h rows [r0, r0+32) -> LDS (async, pre-swizzled source) ----
  {
    int rbase = w * 4;
    #pragma unroll
    for (int i = 0; i < 8; ++i) {
      int r = rbase + (i >> 1);
      int half = i & 1;
      char* ldsb = hls + r * 2048 + half * 1024;    // wave-uniform, linear dest
      int m = half * 64 + l;                         // dest 16B-chunk index
      int srcc = m ^ (r & 7);                        // inverse swizzle on source
      const char* gp = (const char*)hR + (((size_t)(r0 + r) << 10) + srcc * 8) * 2;
      __builtin_amdgcn_global_load_lds(gp, ldsb, 16, 0, 0);
    }
  }

  // ---- per-lane gate constants + c state (latency hidden by staging) ----
  const int q   = w >> 1;
  const int lc  = l & 15;
  const int bcol = hc0 + ((w & 1) << 4) + lc;
  const float* wxp = (q == 0) ? wgx : (q == 1) ? wix : (q == 2) ? wfx : wox;
  const float* bbp = (q == 0) ? bg  : (q == 1) ? bi  : (q == 2) ? bfp : bo;
  const float wxv = wxp[bcol];
  const float bbv = bbp[bcol];

  const int r_a = tid >> 5, hc_a = tid & 31;
  const int r_b = (tid + 512) >> 5;
  const size_t ci_a = (size_t)(r0 + r_a) * Hd + hc0 + hc_a;
  const size_t ci_b = (size_t)(r0 + r_b) * Hd + hc0 + hc_a;
  const float c_a = cbuf[ci_a];
  const float c_b = cbuf[ci_b];

  __syncthreads();   // staging landed; xsh visible

  // ---- acc init = bias + x*wx (C/D layout: col=l&15, row=(l>>4)*4+p) ----
  const int rb4 = (l >> 4) * 4;
  f32x4 acc0, acc1;
  #pragma unroll
  for (int p = 0; p < 4; ++p) {
    acc0[p] = bbv + xsh[rb4 + p] * wxv;
    acc1[p] = bbv + xsh[rb4 + p + 16] * wxv;
  }

  // ---- MFMA loop: A from LDS, B streamed from whT (L2-warm, wave-overlapped) ----
  const int roff0 = lc * 2048;
  const int roff1 = roff0 + 16 * 2048;
  const int swz   = (l & 7) << 4;
  const int kboff = (l >> 4) * 16;
  const unsigned short* wcol = whT + (size_t)(q * 1024 + bcol) * Hd + (l >> 4) * 8;
  #pragma unroll
  for (int kc = 0; kc < 32; ++kc) {
    int boff = (kc * 64 + kboff) ^ swz;
    bf16x8 a0 = *(const bf16x8*)(hls + roff0 + boff);
    bf16x8 a1 = *(const bf16x8*)(hls + roff1 + boff);
    bf16x8 b  = *(const bf16x8*)(wcol + kc * 32);
    acc0 = __builtin_amdgcn_mfma_f32_16x16x32_bf16(a0, b, acc0, 0, 0, 0);
    acc1 = __builtin_amdgcn_mfma_f32_16x16x32_bf16(a1, b, acc1, 0, 0, 0);
  }

  // ---- acc -> zbuf (full z: bias + x-term already included) ----
  {
    int colz = (w << 4) + lc;
    #pragma unroll
    for (int p = 0; p < 4; ++p) {
      zbuf[(rb4 + p) * 128 + colz]      = acc0[p];
      zbuf[(rb4 + p + 16) * 128 + colz] = acc1[p];
    }
  }
  __syncthreads();

  // ---- lean epilogue: gates + c update, write h' and c ----
  float cn_a, cn_b;
  {
    float zg = zbuf[r_a * 128 +       hc_a];
    float zi = zbuf[r_a * 128 +  32 + hc_a];
    float zf = zbuf[r_a * 128 +  64 + hc_a];
    float zo = zbuf[r_a * 128 +  96 + hc_a];
    float G = tanhf_(zg), I = sigmf_(zi), F = sigmf_(zf), O = sigmf_(zo);
    cn_a = G * I + c_a * F;
    hW[ci_a] = f2bf(tanhf_(cn_a) * O);
  }
  {
    float zg = zbuf[r_b * 128 +       hc_a];
    float zi = zbuf[r_b * 128 +  32 + hc_a];
    float zf = zbuf[r_b * 128 +  64 + hc_a];
    float zo = zbuf[r_b * 128 +  96 + hc_a];
    float G = tanhf_(zg), I = sigmf_(zi), F = sigmf_(zf), O = sigmf_(zo);
    cn_b = G * I + c_b * F;
    hW[ci_b] = f2bf(tanhf_(cn_b) * O);
  }
  cbuf[ci_a] = cn_a;
  cbuf[ci_b] = cn_b;
}

// ---- projection + softmax ----
__global__ __launch_bounds__(256) void lstm_final(
    const unsigned short* __restrict__ h, const float* __restrict__ wph,
    const float* __restrict__ bp, float* __restrict__ out)
{
  __shared__ float zrow[16][10];
  const int tid = threadIdx.x;
  if (tid < 160) {
    int rr = tid / 10, c = tid - rr * 10;
    int r = blockIdx.x * 16 + rr;
    float acc = bp[c];
    for (int k8 = 0; k8 < 128; ++k8) {
      bf16x8 hv = *(const bf16x8*)(h + (size_t)r * Hd + k8 * 8);
      #pragma unroll
      for (int e = 0; e < 8; ++e)
        acc += bf2f((unsigned short)hv[e]) * wph[(k8 * 8 + e) * Cc + c];
    }
    zrow[rr][c] = acc;
  }
  __syncthreads();
  if (tid < 16) {
    int r = blockIdx.x * 16 + tid;
    float m = -1e30f;
    #pragma unroll
    for (int cc = 0; cc < Cc; ++cc) m = fmaxf(m, zrow[tid][cc]);
    float s = 0.f;
    float ev[Cc];
    #pragma unroll
    for (int cc = 0; cc < Cc; ++cc) { ev[cc] = __expf(zrow[tid][cc] - m); s += ev[cc]; }
    float inv = 1.0f / s;
    #pragma unroll
    for (int cc = 0; cc < Cc; ++cc) out[r * Cc + cc] = ev[cc] * inv;
  }
}

extern "C" void kernel_launch(void* const* d_in, const int* in_sizes, int n_in,
                              void* d_out, int out_size, void* d_ws, size_t ws_size,
                              hipStream_t stream) {
  const float* x   = (const float*)d_in[0];
  const float* wgx = (const float*)d_in[1];
  const float* wgh = (const float*)d_in[2];
  const float* bg  = (const float*)d_in[3];
  const float* wix = (const float*)d_in[4];
  const float* wih = (const float*)d_in[5];
  const float* bi  = (const float*)d_in[6];
  const float* wfx = (const float*)d_in[7];
  const float* wfh = (const float*)d_in[8];
  const float* bfp = (const float*)d_in[9];
  const float* wox = (const float*)d_in[10];
  const float* woh = (const float*)d_in[11];
  const float* bo  = (const float*)d_in[12];
  const float* wph = (const float*)d_in[13];
  const float* bp  = (const float*)d_in[14];
  float* out = (float*)d_out;

  // d_ws layout: whT 8.0MB | hbuf 2x512KB | cbuf 1MB | xT 512KB
  unsigned short* whT  = (unsigned short*)d_ws;
  unsigned short* hbuf = (unsigned short*)((char*)d_ws + (size_t)4 * 1024 * Hd * 2);
  float* cbuf = (float*)((char*)hbuf + (size_t)2 * HBHALF * 2);
  float* xT   = (float*)((char*)cbuf + (size_t)HBHALF * 4);

  size_t shmem = 65536 + 16384;   // 80KB dynamic (+ static xsh)
  hipFuncSetAttribute((const void*)lstm_step,
                      hipFuncAttributeMaxDynamicSharedMemorySize, (int)shmem);

  lstm_prep<<<1024, 256, 0, stream>>>(wgh, wih, wfh, woh, whT);
  x_prep<<<128, 256, 0, stream>>>(x, xT);

  // t = 0: writes h_1 (parity 1) and c_1 fully -> no memsets needed
  lstm_step0<<<512, 512, 0, stream>>>(xT, wgx, wix, wfx, wox,
                                      bg, bi, bfp, bo,
                                      hbuf + HBHALF, cbuf);

  for (int t = 1; t < Tt; ++t) {
    const unsigned short* hR = hbuf + (size_t)(t & 1) * HBHALF;
    unsigned short*       hW = hbuf + (size_t)((t + 1) & 1) * HBHALF;
    lstm_step<<<256, 512, shmem, stream>>>(whT, xT, wgx, wix, wfx, wox,
                                           bg, bi, bfp, bo, hR, hW, cbuf, t);
  }

  lstm_final<<<16, 256, 0, stream>>>(hbuf /* parity 0 = h_T */, wph, bp, out);
}